// Round 4
// baseline (350.680 us; speedup 1.0000x reference)
//
#include <hip/hip_runtime.h>
#include <stdint.h>

// BMM: out[b,m,n] = round(alpha * sum_k a[b,m,k]*b[b,n,k]), int8 x int8 -> int32
// B=64, M=1024, N=1024, K=128.  Inputs arrive int32-expanded (harness integer
// convention, discovered R2); output 256 MB int32 -> write-bound problem.
//
// R3 changes vs R2 (both target the store stream / overlap):
//  * __launch_bounds__(256,4): 4 blocks/CU (was 2). LDS cut to one 32 KB
//    buffer (A 16K + B 16K, reused as epilogue transpose chunk).
//  * Wave owns a 128x32 C-strip (acc[4] of v16i, 64 VGPR) instead of 64x64;
//    epilogue rounds: dump 32x128 int32 slab to LDS, re-read linearly, store
//    as global_store_dwordx4 -> 1 KB contiguous per wave-instruction
//    (memset-like write pattern; 16 wide stores/thread vs 64 scalar).

typedef int v4i  __attribute__((ext_vector_type(4)));
typedef int v16i __attribute__((ext_vector_type(16)));

__device__ __forceinline__ int pack4(v4i w) {
    // low bytes of 4 int32 -> one dword of 4 int8 (two's complement)
    return (w.x & 0xFF) | ((w.y & 0xFF) << 8) | ((w.z & 0xFF) << 16) | (w.w << 24);
}

__global__ __launch_bounds__(256, 4) void bmm_s8s8_s32_kernel(
    const int*   __restrict__ A,     // [64,1024,128] int32-expanded int8
    const int*   __restrict__ Bm,    // [64,1024,128] int32-expanded int8
    const float* __restrict__ alpha_p,
    int*         __restrict__ out)   // [64,1024,1024]
{
    __shared__ uint8_t smem[32768];
    uint8_t* Als   = smem;           // 16 KB: A tile, int8, XOR-swizzled rows
    uint8_t* Bls   = smem + 16384;   // 16 KB: B tile
    int*     chunk = (int*)smem;     // epilogue: 32x128 int32 slab (16 KB)

    const int tid   = threadIdx.x;
    const int lane  = tid & 63;
    const int wave  = tid >> 6;      // 0..3
    const int half_ = lane >> 5;     // 0..1
    const int lrow  = lane & 31;     // 0..31

    const int bz = blockIdx.z;
    const int m0 = blockIdx.y << 7;
    const int n0 = blockIdx.x << 7;

    const float alpha = *alpha_p;    // uniform -> s_load

    // int32 element bases; each tile row = 128 int32 = 512 B.
    const size_t abase = ((size_t)bz * 1024 + (size_t)m0) * 128;
    const size_t bbase = ((size_t)bz * 1024 + (size_t)n0) * 128;

    // ---- Stage: granule = 16 k-values = 4 dwordx4 int32 loads, packed to
    //      16 int8, stored at swizzled slot gp^(m&7) of LDS row m.
#pragma unroll
    for (int t = 0; t < 4; ++t) {
        const int G  = t * 256 + tid;              // granule 0..1023
        const int m  = G >> 3;                     // tile row
        const int gp = G & 7;                      // granule slot in row
        const size_t goff = (size_t)m * 128 + (size_t)gp * 16;

        v4i a0 = *(const v4i*)(A + abase + goff + 0);
        v4i a1 = *(const v4i*)(A + abase + goff + 4);
        v4i a2 = *(const v4i*)(A + abase + goff + 8);
        v4i a3 = *(const v4i*)(A + abase + goff + 12);
        v4i b0 = *(const v4i*)(Bm + bbase + goff + 0);
        v4i b1 = *(const v4i*)(Bm + bbase + goff + 4);
        v4i b2 = *(const v4i*)(Bm + bbase + goff + 8);
        v4i b3 = *(const v4i*)(Bm + bbase + goff + 12);

        v4i pa = { pack4(a0), pack4(a1), pack4(a2), pack4(a3) };
        v4i pb = { pack4(b0), pack4(b1), pack4(b2), pack4(b3) };

        const int loff = m * 128 + ((gp ^ (m & 7)) << 4);
        *(v4i*)(Als + loff) = pa;
        *(v4i*)(Bls + loff) = pb;
    }
    __syncthreads();

    // ---- Compute: wave w -> cols w*32..w*32+31, all 128 rows.
    //      acc[mi] = 32x32 tile at rows mi*32. 4 K-steps of 32.
    v16i acc[4] = {};

#pragma unroll
    for (int kk = 0; kk < 4; ++kk) {
        const int g = kk * 2 + half_;   // 16B k-granule for this half-wave
        const int n = wave * 32 + lrow;
        const v4i bf = *(const v4i*)(Bls + n * 128 + ((g ^ (n & 7)) << 4));
        v4i af[4];
#pragma unroll
        for (int mi = 0; mi < 4; ++mi) {
            const int m = mi * 32 + lrow;
            af[mi] = *(const v4i*)(Als + m * 128 + ((g ^ (m & 7)) << 4));
        }
#pragma unroll
        for (int mi = 0; mi < 4; ++mi)
            acc[mi] = __builtin_amdgcn_mfma_i32_32x32x32_i8(af[mi], bf, acc[mi], 0, 0, 0);
    }
    __syncthreads();   // all fragment reads done before LDS reuse

    // ---- Epilogue: 4 rounds. Round j: dump acc[j] (rows j*32..+31, cols
    //      wave*32..+31) into the 32x128 slab, then store slab linearly.
    // C/D layout (HW-verified): col=lane&31, row=(r&3)+8*(r>>2)+4*(lane>>5).
    int* outb = out + ((size_t)bz << 20) + n0;

#pragma unroll
    for (int j = 0; j < 4; ++j) {
#pragma unroll
        for (int r = 0; r < 16; ++r) {
            const int row_local = (r & 3) + 8 * (r >> 2) + 4 * half_;
            chunk[row_local * 128 + wave * 32 + lrow] =
                __float2int_rn((float)acc[j][r] * alpha);
        }
        __syncthreads();
#pragma unroll
        for (int p = 0; p < 4; ++p) {
            const int row_local = p * 8 + (tid >> 5);       // 0..31
            const v4i v = *(const v4i*)((const uint8_t*)chunk + p * 4096 + tid * 16);
            *(v4i*)(outb + (size_t)(m0 + j * 32 + row_local) * 1024 + (tid & 31) * 4) = v;
        }
        if (j < 3) __syncthreads();   // slab reused next round
    }
}

extern "C" void kernel_launch(void* const* d_in, const int* in_sizes, int n_in,
                              void* d_out, int out_size, void* d_ws, size_t ws_size,
                              hipStream_t stream) {
    const int*   A     = (const int*)d_in[0];
    const int*   Bm    = (const int*)d_in[1];
    const float* alpha = (const float*)d_in[2];
    int*         out   = (int*)d_out;

    dim3 grid(8, 8, 64);   // n-tiles, m-tiles, batch
    dim3 block(256);
    bmm_s8s8_s32_kernel<<<grid, block, 0, stream>>>(A, Bm, alpha, out);
}

// Round 5
// 323.026 us; speedup vs baseline: 1.0856x; 1.0856x over previous
//
#include <hip/hip_runtime.h>
#include <stdint.h>

// BMM: out[b,m,n] = round(alpha * sum_k a[b,m,k]*b[b,n,k]), int8 x int8 -> int32
// B=64, M=1024, N=1024, K=128.  Inputs arrive int32-expanded (harness integer
// convention); output 256 MB int32.
//
// R4 theory: R2/R3 tied at ~160us kernel time because READ demand dominates:
// int32 inputs mean 128 KB/block staging and 537 MB total read demand (8x
// panel reuse) + 256 MB writes ~= 793 MB vector-memory traffic (~5 TB/s).
// Fix: (1) prepack pass -> int8 in d_ws (read demand drops 4x, GEMM staging
// VALU drops 4x); (2) nontemporal output stores so the 256 MB write stream
// doesn't evict the 16.8 MB packed input set from LLC.

typedef int v4i  __attribute__((ext_vector_type(4)));
typedef int v16i __attribute__((ext_vector_type(16)));

__device__ __forceinline__ int pack4(v4i w) {
    // low bytes of 4 int32 -> one dword of 4 int8 (two's complement)
    return (w.x & 0xFF) | ((w.y & 0xFF) << 8) | ((w.z & 0xFF) << 16) | (w.w << 24);
}

// ---- Pass 1: int32-expanded -> packed int8. 8.39M elems per tensor,
//      16 elems/thread, 2048 blocks x 256 threads.
__global__ __launch_bounds__(256) void prepack_kernel(
    const int* __restrict__ A, const int* __restrict__ Bm,
    uint8_t* __restrict__ Apk, uint8_t* __restrict__ Bpk)
{
    const int g = blockIdx.x * 256 + threadIdx.x;   // granule 0..524287
    const size_t eoff = (size_t)g * 16;             // int32 element offset

    v4i a[4], b[4];
#pragma unroll
    for (int i = 0; i < 4; ++i) {
        a[i] = __builtin_nontemporal_load((const v4i*)(A + eoff) + i);
        b[i] = __builtin_nontemporal_load((const v4i*)(Bm + eoff) + i);
    }
    v4i pa = { pack4(a[0]), pack4(a[1]), pack4(a[2]), pack4(a[3]) };
    v4i pb = { pack4(b[0]), pack4(b[1]), pack4(b[2]), pack4(b[3]) };
    *(v4i*)(Apk + eoff) = pa;   // packed byte offset == elem offset
    *(v4i*)(Bpk + eoff) = pb;
}

// ---- Pass 2: GEMM on packed int8. One 128x128 C-tile per block.
__global__ __launch_bounds__(256, 4) void bmm_s8s8_s32_kernel(
    const uint8_t* __restrict__ Apk,   // [64,1024,128] int8
    const uint8_t* __restrict__ Bpk,   // [64,1024,128] int8
    const float*   __restrict__ alpha_p,
    int*           __restrict__ out)   // [64,1024,1024]
{
    __shared__ uint8_t smem[32768];
    uint8_t* Als   = smem;             // 16 KB, XOR-swizzled rows
    uint8_t* Bls   = smem + 16384;     // 16 KB
    int*     chunk = (int*)smem;       // epilogue 32x128 int32 slab

    const int tid   = threadIdx.x;
    const int lane  = tid & 63;
    const int wave  = tid >> 6;        // 0..3
    const int half_ = lane >> 5;       // 0..1
    const int lrow  = lane & 31;       // 0..31

    const int bz = blockIdx.z;
    const int m0 = blockIdx.y << 7;
    const int n0 = blockIdx.x << 7;

    const float alpha = *alpha_p;

    // Packed tile bases (bytes); each 128-row tile is 16 KB contiguous.
    const size_t abase = ((size_t)bz * 1024 + (size_t)m0) * 128;
    const size_t bbase = ((size_t)bz * 1024 + (size_t)n0) * 128;

    // ---- Stage: 4 granules (16 B) per thread per matrix, coalesced load,
    //      swizzled ds_write: LDS[m][gp^(m&7)] = tile[m][gp].
#pragma unroll
    for (int t = 0; t < 4; ++t) {
        const int G  = t * 256 + tid;              // granule 0..1023
        const int m  = G >> 3;
        const int gp = G & 7;
        const v4i pa = *(const v4i*)(Apk + abase + (size_t)G * 16);
        const v4i pb = *(const v4i*)(Bpk + bbase + (size_t)G * 16);
        const int loff = m * 128 + ((gp ^ (m & 7)) << 4);
        *(v4i*)(Als + loff) = pa;
        *(v4i*)(Bls + loff) = pb;
    }
    __syncthreads();

    // ---- Compute: wave w -> cols w*32..+31, all 128 rows; 4 K-steps of 32.
    v16i acc[4] = {};
#pragma unroll
    for (int kk = 0; kk < 4; ++kk) {
        const int g = kk * 2 + half_;
        const int n = wave * 32 + lrow;
        const v4i bf = *(const v4i*)(Bls + n * 128 + ((g ^ (n & 7)) << 4));
        v4i af[4];
#pragma unroll
        for (int mi = 0; mi < 4; ++mi) {
            const int m = mi * 32 + lrow;
            af[mi] = *(const v4i*)(Als + m * 128 + ((g ^ (m & 7)) << 4));
        }
#pragma unroll
        for (int mi = 0; mi < 4; ++mi)
            acc[mi] = __builtin_amdgcn_mfma_i32_32x32x32_i8(af[mi], bf, acc[mi], 0, 0, 0);
    }
    __syncthreads();   // fragment reads done before LDS reuse

    // ---- Epilogue: 4 rounds of LDS transpose -> 1 KB-wide nontemporal
    //      stores. C/D layout: col=lane&31, row=(r&3)+8*(r>>2)+4*(lane>>5).
    int* outb = out + ((size_t)bz << 20) + n0;

#pragma unroll
    for (int j = 0; j < 4; ++j) {
#pragma unroll
        for (int r = 0; r < 16; ++r) {
            const int row_local = (r & 3) + 8 * (r >> 2) + 4 * half_;
            chunk[row_local * 128 + wave * 32 + lrow] =
                __float2int_rn((float)acc[j][r] * alpha);
        }
        __syncthreads();
#pragma unroll
        for (int p = 0; p < 4; ++p) {
            const int row_local = p * 8 + (tid >> 5);       // 0..31
            const v4i v = *(const v4i*)((const uint8_t*)chunk + p * 4096 + tid * 16);
            __builtin_nontemporal_store(
                v, (v4i*)(outb + (size_t)(m0 + j * 32 + row_local) * 1024 + (tid & 31) * 4));
        }
        if (j < 3) __syncthreads();
    }
}

extern "C" void kernel_launch(void* const* d_in, const int* in_sizes, int n_in,
                              void* d_out, int out_size, void* d_ws, size_t ws_size,
                              hipStream_t stream) {
    const int*   A     = (const int*)d_in[0];
    const int*   Bm    = (const int*)d_in[1];
    const float* alpha = (const float*)d_in[2];
    int*         out   = (int*)d_out;

    uint8_t* Apk = (uint8_t*)d_ws;                 // 8,388,608 B
    uint8_t* Bpk = (uint8_t*)d_ws + (8u << 20);    // 8,388,608 B

    prepack_kernel<<<dim3(2048), dim3(256), 0, stream>>>(A, Bm, Apk, Bpk);

    dim3 grid(8, 8, 64);   // n-tiles, m-tiles, batch
    bmm_s8s8_s32_kernel<<<grid, dim3(256), 0, stream>>>(Apk, Bpk, alpha, out);
}